// Round 2
// baseline (51.813 us; speedup 1.0000x reference)
//
#include <hip/hip_runtime.h>
#include <hip/hip_cooperative_groups.h>
#include <math.h>

namespace cg = cooperative_groups;

#define NB 16          // batch
#define NT 512         // time
#define NC 32          // channels
#define NW 128         // window
#define TILE_T 64
#define NTILES (NT / TILE_T)        // 8
#define NBLK (NB * NTILES)          // 128 blocks (≤256 CUs → all co-resident)
#define NROWS (TILE_T + NW)         // 192 rows staged per block
#define WIN_MIN_F 2.0f
#define WIN_RANGE_F 62.0f           // WIN_MAX - WIN_MIN

__global__ __launch_bounds__(256) void feat_fused(
    const float* __restrict__ x,
    const float* __restrict__ series,
    const int*   __restrict__ indices,
    const float* __restrict__ rwm,
    const float* __restrict__ rws,
    const float* __restrict__ gm, const float* __restrict__ bm,
    const float* __restrict__ gs, const float* __restrict__ bs,
    float* __restrict__ partials,   // NBLK * 4 * NC floats in ws
    float* __restrict__ out)
{
    __shared__ __align__(16) float s_tile[NROWS * NC];   // 24 KB
    __shared__ float s_w1[NW * NC];                      // 16 KB
    __shared__ float s_w2[NW * NC];                      // 16 KB
    __shared__ float s_inv1[NC], s_inv2[NC];
    __shared__ float s_red[4 * 8 * NC];                  // 4 KB (reused in phase B)

    const int tid = threadIdx.x;
    const int blk = blockIdx.x;
    const int b   = blk >> 3;
    const int tt  = blk & 7;
    const int t0  = tt * TILE_T;
    const int start = indices[2 * b];

    // ---- weight tables: w[j][c] = sigmoid(win[c] - (NW-1-j)) ----
    for (int i = tid; i < NW * NC; i += 256) {
        const int w = i >> 5, c = i & 31;
        const float age = (float)(NW - 1 - w);
        const float win_m = WIN_MIN_F + WIN_RANGE_F / (1.0f + expf(-rwm[c]));
        const float win_s = WIN_MIN_F + WIN_RANGE_F / (1.0f + expf(-rws[c]));
        s_w1[i] = 1.0f / (1.0f + expf(-(win_m - age)));
        s_w2[i] = 1.0f / (1.0f + expf(-(win_s - age)));
    }

    // ---- stage contiguous series slice: rows [start-NW+t0, +NROWS) ----
    const float4* src4 = (const float4*)(series + (size_t)(start - NW + t0) * NC);
    float4* dst4 = (float4*)s_tile;
    for (int j = tid; j < NROWS * NC / 4; j += 256)
        dst4[j] = src4[j];

    __syncthreads();

    if (tid < NC) {
        float s1 = 0.f, s2 = 0.f;
        for (int w = 0; w < NW; ++w) {
            s1 += s_w1[w * NC + tid];
            s2 += s_w2[w * NC + tid];
        }
        s_inv1[tid] = 1.0f / s1;
        s_inv2[tid] = 1.0f / s2;
    }
    __syncthreads();

    // ---- phase A: each thread owns channel c, 8 t-rows ----
    const int c  = tid & 31;
    const int tg = tid >> 5;          // 0..7
    const float inv1 = s_inv1[c], inv2 = s_inv2[c];

    float a1[8], a2[8], a3[8];
#pragma unroll
    for (int k = 0; k < 8; ++k) { a1[k] = 0.f; a2[k] = 0.f; a3[k] = 0.f; }

    const int tbase = tg * 8;
#pragma unroll 4
    for (int w = 0; w < NW; ++w) {
        const float w1 = s_w1[w * NC + c];
        const float w2 = s_w2[w * NC + c];
#pragma unroll
        for (int k = 0; k < 8; ++k) {
            const float xv = s_tile[(tbase + k + w) * NC + c];
            a1[k] = fmaf(xv, w1, a1[k]);
            a2[k] = fmaf(xv, w2, a2[k]);
            a3[k] = fmaf(xv * xv, w2, a3[k]);
        }
    }

    float fm[8], fs[8];                    // live across grid.sync in registers
    float p0 = 0.f, p1 = 0.f, p2 = 0.f, p3 = 0.f;
#pragma unroll
    for (int k = 0; k < 8; ++k) {
        fm[k] = a1[k] * inv1;
        const float m2 = a2[k] * inv2;
        float var = a3[k] * inv2 - m2 * m2;
        var = fmaxf(var, 0.0f);
        fs[k] = sqrtf(var + 1e-8f);
        p0 += fm[k]; p1 += fm[k] * fm[k]; p2 += fs[k]; p3 += fs[k] * fs[k];
    }

    s_red[(0 * 8 + tg) * NC + c] = p0;
    s_red[(1 * 8 + tg) * NC + c] = p1;
    s_red[(2 * 8 + tg) * NC + c] = p2;
    s_red[(3 * 8 + tg) * NC + c] = p3;
    __syncthreads();

    if (tid < 4 * NC) {
        const int a = tid >> 5, cc = tid & 31;
        float s = 0.f;
#pragma unroll
        for (int g = 0; g < 8; ++g) s += s_red[(a * 8 + g) * NC + cc];
        partials[blk * (4 * NC) + a * NC + cc] = s;
    }

    // ---- grid-wide barrier (device-scope fence included) ----
    cg::this_grid().sync();

    // ---- phase B: every block redundantly reduces partials -> coeffs ----
    // s_red reuse: [0,256) half-sums, [256,384) sums, [384,512) coeffs
    float* s_half = s_red;
    float* s_sums = s_red + 256;
    float* s_coef = s_red + 384;
    {
        const int idx  = tid & 127;        // (a*NC + c)
        const int half = tid >> 7;         // 0/1
        float s = 0.f;
        const float* p = partials + half * 64 * (4 * NC) + idx;
#pragma unroll 8
        for (int bb = 0; bb < 64; ++bb)
            s += p[bb * (4 * NC)];
        s_half[half * 128 + idx] = s;
    }
    __syncthreads();
    if (tid < 128) s_sums[tid] = s_half[tid] + s_half[128 + tid];
    __syncthreads();
    if (tid < NC) {
        const float invN = 1.0f / (float)(NB * NT);
        const float mu_m  = s_sums[0 * NC + tid] * invN;
        float var_m = s_sums[1 * NC + tid] * invN - mu_m * mu_m;
        var_m = fmaxf(var_m, 0.0f);
        const float A1 = gm[tid] / sqrtf(var_m + 1e-5f);
        const float B1 = bm[tid] - mu_m * A1;
        const float mu_s  = s_sums[2 * NC + tid] * invN;
        float var_s = s_sums[3 * NC + tid] * invN - mu_s * mu_s;
        var_s = fmaxf(var_s, 0.0f);
        const float A2 = gs[tid] / sqrtf(var_s + 1e-5f);
        const float B2 = bs[tid] - mu_s * A2;
        s_coef[0 * NC + tid] = A1;
        s_coef[1 * NC + tid] = B1;
        s_coef[2 * NC + tid] = A2;
        s_coef[3 * NC + tid] = B2;
    }
    __syncthreads();

    // ---- phase C: write 64 rows of [x | BN(fm) | BN(fs)] ----
    const float A1 = s_coef[c],           B1 = s_coef[NC + c];
    const float A2 = s_coef[2 * NC + c],  B2 = s_coef[3 * NC + c];
#pragma unroll
    for (int k = 0; k < 8; ++k) {
        const int row = b * NT + t0 + tbase + k;
        const size_t i32 = (size_t)row * NC + c;
        const size_t o   = (size_t)row * 96;
        out[o + c]      = x[i32];
        out[o + 32 + c] = fmaf(fm[k], A1, B1);
        out[o + 64 + c] = fmaf(fs[k], A2, B2);
    }
}

extern "C" void kernel_launch(void* const* d_in, const int* in_sizes, int n_in,
                              void* d_out, int out_size, void* d_ws, size_t ws_size,
                              hipStream_t stream) {
    const float* x      = (const float*)d_in[0];
    const float* series = (const float*)d_in[1];
    const int*   idx    = (const int*)d_in[2];
    const float* rwm    = (const float*)d_in[3];
    const float* rws    = (const float*)d_in[4];
    const float* gm     = (const float*)d_in[5];
    const float* bm     = (const float*)d_in[6];
    const float* gs     = (const float*)d_in[7];
    const float* bs     = (const float*)d_in[8];
    float* out      = (float*)d_out;
    float* partials = (float*)d_ws;

    void* args[] = {
        (void*)&x, (void*)&series, (void*)&idx, (void*)&rwm, (void*)&rws,
        (void*)&gm, (void*)&bm, (void*)&gs, (void*)&bs,
        (void*)&partials, (void*)&out
    };
    hipLaunchCooperativeKernel((const void*)feat_fused, dim3(NBLK), dim3(256),
                               args, 0, stream);
}

// Round 3
// 22.922 us; speedup vs baseline: 2.2604x; 2.2604x over previous
//
#include <hip/hip_runtime.h>
#include <math.h>

#define NB 16          // batch
#define NT 512         // time
#define NC 32          // channels
#define NW 128         // window
#define TILE_T 64
#define NTILES (NT / TILE_T)        // 8
#define NBLK (NB * NTILES)          // 128
#define NROWS (TILE_T + NW)         // 192 rows staged per block
#define WIN_MIN_F 2.0f
#define WIN_RANGE_F 62.0f           // WIN_MAX - WIN_MIN

// ws layout (floats):
// [0, NB*NT*NC)            f_mean
// [NB*NT*NC, 2*NB*NT*NC)   f_std
// then partials: NBLK * 4 * NC
#define WS_FMEAN 0
#define WS_FSTD  (NB*NT*NC)
#define WS_PART  (2*NB*NT*NC)

__global__ __launch_bounds__(256) void feat_main(
    const float* __restrict__ series,
    const int*   __restrict__ indices,
    const float* __restrict__ rwm,
    const float* __restrict__ rws,
    float* __restrict__ f_mean,
    float* __restrict__ f_std,
    float* __restrict__ partials)
{
    __shared__ __align__(16) float s_tile[NROWS * NC];   // 24 KB
    __shared__ float s_w1[NW * NC];                      // 16 KB
    __shared__ float s_w2[NW * NC];                      // 16 KB
    __shared__ float s_win[2 * NC];
    __shared__ float s_inv1[NC], s_inv2[NC];
    __shared__ float s_red[4 * 8 * NC];                  // 4 KB

    const int tid = threadIdx.x;
    const int blk = blockIdx.x;
    const int b   = blk >> 3;
    const int tt  = blk & 7;
    const int t0  = tt * TILE_T;
    const int start = indices[2 * b];

    // hoisted per-channel window sizes (one sigmoid each)
    if (tid < NC) {
        s_win[tid]      = WIN_MIN_F + WIN_RANGE_F / (1.0f + expf(-rwm[tid]));
        s_win[NC + tid] = WIN_MIN_F + WIN_RANGE_F / (1.0f + expf(-rws[tid]));
    }

    // ---- stage contiguous series slice: rows [start-NW+t0, +NROWS) ----
    const float4* src4 = (const float4*)(series + (size_t)(start - NW + t0) * NC);
    float4* dst4 = (float4*)s_tile;
    for (int j = tid; j < NROWS * NC / 4; j += 256)
        dst4[j] = src4[j];
    __syncthreads();

    // ---- weight tables: w[j][c] = sigmoid(win[c] - (NW-1-j)) ----
    for (int i = tid; i < NW * NC; i += 256) {
        const int w = i >> 5, c = i & 31;
        const float age = (float)(NW - 1 - w);
        s_w1[i] = 1.0f / (1.0f + expf(-(s_win[c] - age)));
        s_w2[i] = 1.0f / (1.0f + expf(-(s_win[NC + c] - age)));
    }
    __syncthreads();

    if (tid < NC) {
        float s1 = 0.f, s2 = 0.f;
        for (int w = 0; w < NW; ++w) {
            s1 += s_w1[w * NC + tid];
            s2 += s_w2[w * NC + tid];
        }
        s_inv1[tid] = 1.0f / s1;
        s_inv2[tid] = 1.0f / s2;
    }
    __syncthreads();

    // ---- main compute: each thread owns channel c, 8 t-rows ----
    const int c  = tid & 31;
    const int tg = tid >> 5;
    const float inv1 = s_inv1[c], inv2 = s_inv2[c];

    float a1[8], a2[8], a3[8];
#pragma unroll
    for (int k = 0; k < 8; ++k) { a1[k] = 0.f; a2[k] = 0.f; a3[k] = 0.f; }

    const int tbase = tg * 8;
#pragma unroll 4
    for (int w = 0; w < NW; ++w) {
        const float w1 = s_w1[w * NC + c];
        const float w2 = s_w2[w * NC + c];
#pragma unroll
        for (int k = 0; k < 8; ++k) {
            const float xv = s_tile[(tbase + k + w) * NC + c];
            a1[k] = fmaf(xv, w1, a1[k]);
            a2[k] = fmaf(xv, w2, a2[k]);
            a3[k] = fmaf(xv * xv, w2, a3[k]);
        }
    }

    float p0 = 0.f, p1 = 0.f, p2 = 0.f, p3 = 0.f;
#pragma unroll
    for (int k = 0; k < 8; ++k) {
        const float fm = a1[k] * inv1;
        const float m2 = a2[k] * inv2;
        float var = a3[k] * inv2 - m2 * m2;
        var = fmaxf(var, 0.0f);
        const float fs = sqrtf(var + 1e-8f);
        const int t = t0 + tbase + k;
        const size_t o = ((size_t)b * NT + t) * NC + c;
        f_mean[o] = fm;
        f_std[o]  = fs;
        p0 += fm; p1 += fm * fm; p2 += fs; p3 += fs * fs;
    }

    s_red[(0 * 8 + tg) * NC + c] = p0;
    s_red[(1 * 8 + tg) * NC + c] = p1;
    s_red[(2 * 8 + tg) * NC + c] = p2;
    s_red[(3 * 8 + tg) * NC + c] = p3;
    __syncthreads();

    if (tid < 4 * NC) {
        const int a = tid >> 5, cc = tid & 31;
        float s = 0.f;
#pragma unroll
        for (int g = 0; g < 8; ++g) s += s_red[(a * 8 + g) * NC + cc];
        partials[blk * (4 * NC) + a * NC + cc] = s;
    }
}

// fused BN-reduce (redundant per block) + writeout: 128 blocks x 64 rows
__global__ __launch_bounds__(256) void bn_write(
    const float* __restrict__ x,
    const float* __restrict__ f_mean,
    const float* __restrict__ f_std,
    const float* __restrict__ partials,
    const float* __restrict__ gm, const float* __restrict__ bm,
    const float* __restrict__ gs, const float* __restrict__ bs,
    float* __restrict__ out)
{
    __shared__ float s_half[2 * 128];
    __shared__ float s_sums[4 * NC];
    __shared__ float s_coef[4 * NC];

    const int tid = threadIdx.x;

    // redundant reduction of partials (64 KB, L2-resident)
    {
        const int idx  = tid & 127;        // (a*NC + c)
        const int half = tid >> 7;         // 0/1
        float s = 0.f;
        const float* p = partials + half * 64 * (4 * NC) + idx;
#pragma unroll 8
        for (int bb = 0; bb < 64; ++bb)
            s += p[bb * (4 * NC)];
        s_half[half * 128 + idx] = s;
    }
    __syncthreads();
    if (tid < 128) s_sums[tid] = s_half[tid] + s_half[128 + tid];
    __syncthreads();
    if (tid < NC) {
        const float invN = 1.0f / (float)(NB * NT);
        const float mu_m  = s_sums[0 * NC + tid] * invN;
        float var_m = s_sums[1 * NC + tid] * invN - mu_m * mu_m;
        var_m = fmaxf(var_m, 0.0f);
        const float A1 = gm[tid] / sqrtf(var_m + 1e-5f);
        const float B1 = bm[tid] - mu_m * A1;
        const float mu_s  = s_sums[2 * NC + tid] * invN;
        float var_s = s_sums[3 * NC + tid] * invN - mu_s * mu_s;
        var_s = fmaxf(var_s, 0.0f);
        const float A2 = gs[tid] / sqrtf(var_s + 1e-5f);
        const float B2 = bs[tid] - mu_s * A2;
        s_coef[0 * NC + tid] = A1;
        s_coef[1 * NC + tid] = B1;
        s_coef[2 * NC + tid] = A2;
        s_coef[3 * NC + tid] = B2;
    }
    __syncthreads();

    const int c  = tid & 31;
    const int tg = tid >> 5;
    const float A1 = s_coef[c],          B1 = s_coef[NC + c];
    const float A2 = s_coef[2 * NC + c], B2 = s_coef[3 * NC + c];

    const int row0 = blockIdx.x * 64 + tg * 8;   // b*NT + t base
#pragma unroll
    for (int k = 0; k < 8; ++k) {
        const int row = row0 + k;
        const size_t i32 = (size_t)row * NC + c;
        const size_t o   = (size_t)row * 96;
        out[o + c]      = x[i32];
        out[o + 32 + c] = fmaf(f_mean[i32], A1, B1);
        out[o + 64 + c] = fmaf(f_std[i32],  A2, B2);
    }
}

extern "C" void kernel_launch(void* const* d_in, const int* in_sizes, int n_in,
                              void* d_out, int out_size, void* d_ws, size_t ws_size,
                              hipStream_t stream) {
    const float* x      = (const float*)d_in[0];
    const float* series = (const float*)d_in[1];
    const int*   idx    = (const int*)d_in[2];
    const float* rwm    = (const float*)d_in[3];
    const float* rws    = (const float*)d_in[4];
    const float* gm     = (const float*)d_in[5];
    const float* bm     = (const float*)d_in[6];
    const float* gs     = (const float*)d_in[7];
    const float* bs     = (const float*)d_in[8];
    float* out = (float*)d_out;
    float* ws  = (float*)d_ws;

    float* f_mean   = ws + WS_FMEAN;
    float* f_std    = ws + WS_FSTD;
    float* partials = ws + WS_PART;

    feat_main<<<NBLK, 256, 0, stream>>>(series, idx, rwm, rws, f_mean, f_std, partials);
    bn_write<<<NBLK, 256, 0, stream>>>(x, f_mean, f_std, partials, gm, bm, gs, bs, out);
}

// Round 4
// 21.384 us; speedup vs baseline: 2.4230x; 1.0719x over previous
//
#include <hip/hip_runtime.h>
#include <math.h>

#define NB 16          // batch
#define NT 512         // time
#define NC 32          // channels
#define NW 128         // window
#define TILE_T 32
#define NTILES (NT / TILE_T)        // 16
#define NBLK (NB * NTILES)          // 256 blocks -> one per CU
#define NROWS (TILE_T + NW)         // 160 rows staged per block
#define WIN_MIN_F 2.0f
#define WIN_RANGE_F 62.0f           // WIN_MAX - WIN_MIN

// ws layout (floats):
// [0, NB*NT*NC)            f_mean
// [NB*NT*NC, 2*NB*NT*NC)   f_std
// then partials: NBLK * 4 * NC
#define WS_FMEAN 0
#define WS_FSTD  (NB*NT*NC)
#define WS_PART  (2*NB*NT*NC)

__device__ __forceinline__ float fast_sigmoid_neg(float a) {
    // sigmoid(-a) = 1/(1+exp(a))
    return __builtin_amdgcn_rcpf(1.0f + __expf(a));
}

__global__ __launch_bounds__(256) void feat_main(
    const float* __restrict__ series,
    const int*   __restrict__ indices,
    const float* __restrict__ rwm,
    const float* __restrict__ rws,
    float* __restrict__ f_mean,
    float* __restrict__ f_std,
    float* __restrict__ partials)
{
    __shared__ __align__(16) float s_tile[NROWS * NC];   // 20 KB
    __shared__ float s_w1[NW * NC];                      // 16 KB
    __shared__ float s_w2[NW * NC];                      // 16 KB
    __shared__ float s_win[2 * NC];
    __shared__ float s_red[4 * 8 * NC];                  // 4 KB

    const int tid = threadIdx.x;
    const int blk = blockIdx.x;
    const int b   = blk >> 4;          // / NTILES
    const int tt  = blk & 15;
    const int t0  = tt * TILE_T;
    const int start = indices[2 * b];

    // per-channel soft window sizes (one fast sigmoid each)
    if (tid < 2 * NC) {
        const float raw = (tid < NC) ? rwm[tid] : rws[tid - NC];
        s_win[tid] = WIN_MIN_F + WIN_RANGE_F * fast_sigmoid_neg(-raw);
    }

    // ---- stage contiguous series slice: rows [start-NW+t0, +NROWS) ----
    const float4* src4 = (const float4*)(series + (size_t)(start - NW + t0) * NC);
    float4* dst4 = (float4*)s_tile;
#pragma unroll
    for (int j = tid; j < NROWS * NC / 4; j += 256)
        dst4[j] = src4[j];
    __syncthreads();

    // ---- weight tables: w[j][c] = sigmoid(win[c] - (NW-1-j)) = 1/(1+exp(age-win)) ----
    for (int i = tid; i < NW * NC; i += 256) {
        const int w = i >> 5, c = i & 31;
        const float age = (float)(NW - 1 - w);
        s_w1[i] = fast_sigmoid_neg(age - s_win[c]);
        s_w2[i] = fast_sigmoid_neg(age - s_win[NC + c]);
    }
    __syncthreads();

    // ---- main compute: thread owns channel c, 4 t-rows; sliding x/x^2 regs ----
    const int c  = tid & 31;
    const int tg = tid >> 5;           // 0..7
    const int tbase = tg * 4;          // rows tbase..tbase+3 of the 32-row tile

    float a1[4], a2[4], a3[4], xs[4], xq[4];
#pragma unroll
    for (int k = 0; k < 4; ++k) {
        a1[k] = 0.f; a2[k] = 0.f; a3[k] = 0.f;
        xs[k] = s_tile[(tbase + k) * NC + c];
        xq[k] = xs[k] * xs[k];
    }

    float s1 = 0.f, s2 = 0.f;
#pragma unroll 8
    for (int w = 0; w < NW; ++w) {
        const float w1 = s_w1[w * NC + c];
        const float w2 = s_w2[w * NC + c];
        s1 += w1; s2 += w2;
#pragma unroll
        for (int k = 0; k < 4; ++k) {
            a1[k] = fmaf(xs[k], w1, a1[k]);
            a2[k] = fmaf(xs[k], w2, a2[k]);
            a3[k] = fmaf(xq[k], w2, a3[k]);
        }
        // slide window by one row (copies vanish under unroll renaming)
        xs[0] = xs[1]; xs[1] = xs[2]; xs[2] = xs[3];
        xq[0] = xq[1]; xq[1] = xq[2]; xq[2] = xq[3];
        const float xn = s_tile[(tbase + 4 + w) * NC + c];   // max idx 159: in bounds
        xs[3] = xn; xq[3] = xn * xn;
    }

    const float inv1 = __builtin_amdgcn_rcpf(s1);
    const float inv2 = __builtin_amdgcn_rcpf(s2);

    float p0 = 0.f, p1 = 0.f, p2 = 0.f, p3 = 0.f;
#pragma unroll
    for (int k = 0; k < 4; ++k) {
        const float fm = a1[k] * inv1;
        const float m2 = a2[k] * inv2;
        float var = a3[k] * inv2 - m2 * m2;
        var = fmaxf(var, 0.0f);
        const float fs = sqrtf(var + 1e-8f);
        const int t = t0 + tbase + k;
        const size_t o = ((size_t)b * NT + t) * NC + c;
        f_mean[o] = fm;
        f_std[o]  = fs;
        p0 += fm; p1 += fm * fm; p2 += fs; p3 += fs * fs;
    }

    s_red[(0 * 8 + tg) * NC + c] = p0;
    s_red[(1 * 8 + tg) * NC + c] = p1;
    s_red[(2 * 8 + tg) * NC + c] = p2;
    s_red[(3 * 8 + tg) * NC + c] = p3;
    __syncthreads();

    if (tid < 4 * NC) {
        const int a = tid >> 5, cc = tid & 31;
        float s = 0.f;
#pragma unroll
        for (int g = 0; g < 8; ++g) s += s_red[(a * 8 + g) * NC + cc];
        partials[blk * (4 * NC) + a * NC + cc] = s;
    }
}

// fused BN-reduce (redundant per block) + writeout: 128 blocks x 64 rows
__global__ __launch_bounds__(256) void bn_write(
    const float* __restrict__ x,
    const float* __restrict__ f_mean,
    const float* __restrict__ f_std,
    const float* __restrict__ partials,
    const float* __restrict__ gm, const float* __restrict__ bm,
    const float* __restrict__ gs, const float* __restrict__ bs,
    float* __restrict__ out)
{
    __shared__ float s_half[2 * 128];
    __shared__ float s_sums[4 * NC];
    __shared__ float s_coef[4 * NC];

    const int tid = threadIdx.x;

    // redundant reduction of partials (128 KB, L2-resident): NBLK=256 entries
    {
        const int idx  = tid & 127;        // (a*NC + c)
        const int half = tid >> 7;         // 0/1
        float s = 0.f;
        const float* p = partials + (size_t)half * 128 * (4 * NC) + idx;
#pragma unroll 8
        for (int bb = 0; bb < 128; ++bb)
            s += p[bb * (4 * NC)];
        s_half[half * 128 + idx] = s;
    }
    __syncthreads();
    if (tid < 128) s_sums[tid] = s_half[tid] + s_half[128 + tid];
    __syncthreads();
    if (tid < NC) {
        const float invN = 1.0f / (float)(NB * NT);
        const float mu_m  = s_sums[0 * NC + tid] * invN;
        float var_m = s_sums[1 * NC + tid] * invN - mu_m * mu_m;
        var_m = fmaxf(var_m, 0.0f);
        const float A1 = gm[tid] / sqrtf(var_m + 1e-5f);
        const float B1 = bm[tid] - mu_m * A1;
        const float mu_s  = s_sums[2 * NC + tid] * invN;
        float var_s = s_sums[3 * NC + tid] * invN - mu_s * mu_s;
        var_s = fmaxf(var_s, 0.0f);
        const float A2 = gs[tid] / sqrtf(var_s + 1e-5f);
        const float B2 = bs[tid] - mu_s * A2;
        s_coef[0 * NC + tid] = A1;
        s_coef[1 * NC + tid] = B1;
        s_coef[2 * NC + tid] = A2;
        s_coef[3 * NC + tid] = B2;
    }
    __syncthreads();

    const int c  = tid & 31;
    const int tg = tid >> 5;
    const float A1 = s_coef[c],          B1 = s_coef[NC + c];
    const float A2 = s_coef[2 * NC + c], B2 = s_coef[3 * NC + c];

    const int row0 = blockIdx.x * 64 + tg * 8;   // b*NT + t base
#pragma unroll
    for (int k = 0; k < 8; ++k) {
        const int row = row0 + k;
        const size_t i32 = (size_t)row * NC + c;
        const size_t o   = (size_t)row * 96;
        out[o + c]      = x[i32];
        out[o + 32 + c] = fmaf(f_mean[i32], A1, B1);
        out[o + 64 + c] = fmaf(f_std[i32],  A2, B2);
    }
}

extern "C" void kernel_launch(void* const* d_in, const int* in_sizes, int n_in,
                              void* d_out, int out_size, void* d_ws, size_t ws_size,
                              hipStream_t stream) {
    const float* x      = (const float*)d_in[0];
    const float* series = (const float*)d_in[1];
    const int*   idx    = (const int*)d_in[2];
    const float* rwm    = (const float*)d_in[3];
    const float* rws    = (const float*)d_in[4];
    const float* gm     = (const float*)d_in[5];
    const float* bm     = (const float*)d_in[6];
    const float* gs     = (const float*)d_in[7];
    const float* bs     = (const float*)d_in[8];
    float* out = (float*)d_out;
    float* ws  = (float*)d_ws;

    float* f_mean   = ws + WS_FMEAN;
    float* f_std    = ws + WS_FSTD;
    float* partials = ws + WS_PART;

    feat_main<<<NBLK, 256, 0, stream>>>(series, idx, rwm, rws, f_mean, f_std, partials);
    bn_write<<<NB * NT / 64, 256, 0, stream>>>(x, f_mean, f_std, partials, gm, bm, gs, bs, out);
}